// Round 4
// baseline (29.972 us; speedup 1.0000x reference)
//
#include <hip/hip_runtime.h>

// out[i, j] = (j >= k_i) ? 1 : 0 with k_i = (int)(rint(x_i*8)/8 * 2048)
//           = rint(x_i*8) * 256  -> always a multiple of 256.
// jnp.round = round-half-to-even = rintf (default RNE rounding mode).
// Output 8192 x 4096 fp32 = 128 MiB -> pure HBM-write-bound.
// k multiple of 256 -> every float4 in a row is uniform (no lane masks).
//
// R4 = R3 with the nontemporal store fixed: __builtin_nontemporal_store
// requires a clang ext_vector type, not HIP's float4 class.

#define IN_CHANNEL 4096
#define BATCH 8192
#define ROW_F4 (IN_CHANNEL / 4)   // 1024 float4 per row
#define ROWS_PER_BLOCK 4

typedef float f32x4 __attribute__((ext_vector_type(4)));

__global__ void __launch_bounds__(256) embprob_kernel(
    const float* __restrict__ x, f32x4* __restrict__ out) {
    const int row0 = blockIdx.x * ROWS_PER_BLOCK;
    const int t = threadIdx.x;

    #pragma unroll
    for (int r = 0; r < ROWS_PER_BLOCK; ++r) {
        const int row = row0 + r;
        const float xv = x[row];                    // wave-uniform -> scalar load
        const int k = (int)rintf(xv * 8.0f) * 256;  // cutoff col, multiple of 256
        f32x4* rowp = out + (size_t)row * ROW_F4;
        #pragma unroll
        for (int u = 0; u < 4; ++u) {
            const int f4 = t + u * 256;             // float4 index within row
            const int col = f4 << 2;                // element column
            const float v = (col >= k) ? 1.0f : 0.0f;
            f32x4 val = {v, v, v, v};
            __builtin_nontemporal_store(val, rowp + f4);
        }
    }
}

extern "C" void kernel_launch(void* const* d_in, const int* in_sizes, int n_in,
                              void* d_out, int out_size, void* d_ws, size_t ws_size,
                              hipStream_t stream) {
    const float* x = (const float*)d_in[0];
    f32x4* out = (f32x4*)d_out;
    embprob_kernel<<<BATCH / ROWS_PER_BLOCK, 256, 0, stream>>>(x, out);
}

// Round 5
// 24.370 us; speedup vs baseline: 1.2298x; 1.2298x over previous
//
#include <hip/hip_runtime.h>

// out[i, j] = (j >= k_i) ? 1 : 0 with k_i = (int)(rint(x_i*8)/8 * 2048)
//           = rint(x_i*8) * 256  -> always a multiple of 256.
// jnp.round = round-half-to-even = rintf (default RNE rounding mode).
// Output 8192 x 4096 fp32 = 128 MiB -> pure HBM-write-bound.
// k multiple of 256 -> every float4 in a row is uniform (no lane masks).
//
// R5 = R4 WITHOUT nontemporal stores (nt regressed 24.6 -> 30.0 us:
// bypassing L2 write-coalescing hurts streaming stores on gfx950).
// Keeps 2048 blocks x 4 rows to A/B block-count vs R2's 8192 x 1 (24.6 us).

#define IN_CHANNEL 4096
#define BATCH 8192
#define ROW_F4 (IN_CHANNEL / 4)   // 1024 float4 per row
#define ROWS_PER_BLOCK 4

typedef float f32x4 __attribute__((ext_vector_type(4)));

__global__ void __launch_bounds__(256) embprob_kernel(
    const float* __restrict__ x, f32x4* __restrict__ out) {
    const int row0 = blockIdx.x * ROWS_PER_BLOCK;
    const int t = threadIdx.x;

    #pragma unroll
    for (int r = 0; r < ROWS_PER_BLOCK; ++r) {
        const int row = row0 + r;
        const float xv = x[row];                    // wave-uniform -> scalar load
        const int k = (int)rintf(xv * 8.0f) * 256;  // cutoff col, multiple of 256
        f32x4* rowp = out + (size_t)row * ROW_F4;
        #pragma unroll
        for (int u = 0; u < 4; ++u) {
            const int f4 = t + u * 256;             // float4 index within row
            const int col = f4 << 2;                // element column
            const float v = (col >= k) ? 1.0f : 0.0f;
            f32x4 val = {v, v, v, v};
            rowp[f4] = val;
        }
    }
}

extern "C" void kernel_launch(void* const* d_in, const int* in_sizes, int n_in,
                              void* d_out, int out_size, void* d_ws, size_t ws_size,
                              hipStream_t stream) {
    const float* x = (const float*)d_in[0];
    f32x4* out = (f32x4*)d_out;
    embprob_kernel<<<BATCH / ROWS_PER_BLOCK, 256, 0, stream>>>(x, out);
}